// Round 10
// baseline (505.987 us; speedup 1.0000x reference)
//
#include <hip/hip_runtime.h>
#include <hip/hip_bf16.h>

#define LN_EPS 1e-5f

typedef float  f32x4  __attribute__((ext_vector_type(4)));
typedef short  bf16x8 __attribute__((ext_vector_type(8)));

// RNE float->bf16 (finite inputs)
static __device__ __forceinline__ short f2bf(float x) {
    unsigned u = __float_as_uint(x);
    unsigned r = (u + 0x7fffu + ((u >> 16) & 1u)) >> 16;
    return (short)r;
}

// XOR swizzle: spread 16B chunks of row-major LDS rows across banks
#define SWZ(r, b) ((b) ^ (((r) & 7) << 4))

// ---------------- prep: convert W_proj/W_sp/W_view to bf16 in ws ----------------
__global__ void k_prep(const float* __restrict__ Wp, const float* __restrict__ Ws,
                       const float* __restrict__ Wv, short* __restrict__ wbuf) {
    int i = blockIdx.x * 256 + threadIdx.x;
    if (i < 16384)      wbuf[i] = f2bf(Wp[i]);
    else if (i < 49152) wbuf[i] = f2bf(Ws[i - 16384]);
    else if (i < 81920) wbuf[i] = f2bf(Wv[i - 49152]);
}

// ---------------- bias: LN+ReLU(global row) @ W_g.T + b_proj -> bias[128] ----------------
__global__ void k_bias(const float* __restrict__ gf, const float* __restrict__ gg,
                       const float* __restrict__ gb, const float* __restrict__ Wg,
                       const float* __restrict__ bp, float* __restrict__ bias) {
    __shared__ float sm[256];
    __shared__ float red[8];
    int t = threadIdx.x;
    float x = gf[t];
    float s = x;
    #pragma unroll
    for (int o = 32; o > 0; o >>= 1) s += __shfl_xor(s, o, 64);
    if ((t & 63) == 0) red[t >> 6] = s;
    __syncthreads();
    float m = (red[0] + red[1] + red[2] + red[3]) * (1.0f / 256.0f);
    float d = x - m;
    float q = d * d;
    #pragma unroll
    for (int o = 32; o > 0; o >>= 1) q += __shfl_xor(q, o, 64);
    if ((t & 63) == 0) red[4 + (t >> 6)] = q;
    __syncthreads();
    float v = (red[4] + red[5] + red[6] + red[7]) * (1.0f / 256.0f);
    float n = fmaxf(d * rsqrtf(v + LN_EPS) * gg[t] + gb[t], 0.0f);
    sm[t] = n;
    __syncthreads();
    if (t < 128) {
        float acc = bp[t];
        const float* wrow = Wg + t * 256;
        #pragma unroll 8
        for (int k = 0; k < 256; ++k) acc = fmaf(sm[k], wrow[k], acc);
        bias[t] = acc;
    }
}

// ---------------- fused LN+ReLU+GEMM: A[M][256] -> out[M][128] ----------------
// block = 256 threads, 64 rows/block; W (bf16 [128][256]) staged in 2 halves of 64 rows.
// MFMA computes D = W_frag x A_frag so each lane holds 4 consecutive out-cols of one row.
__global__ __launch_bounds__(256) void k_ln_gemm(
    const float* __restrict__ A, const float* __restrict__ g, const float* __restrict__ b,
    const short* __restrict__ Wb, float* __restrict__ out, int M)
{
    __shared__ char smem[65536];          // [0,32768): A bf16 [64][256] swizzled; [32768,65536): W half
    char* As = smem;
    char* Wc = smem + 32768;

    const int t  = threadIdx.x;
    const int l  = t & 63;
    const int w  = t >> 6;
    const int rb = blockIdx.x * 64;

    // ---- LN + ReLU -> As (bf16, swizzled). 4 lanes per row, 64 cols each ----
    {
        int lr  = w * 16 + (l >> 2);
        int row = min(rb + lr, M - 1);
        const float* src = A + (size_t)row * 256 + (l & 3) * 64;
        float s = 0.f, s2 = 0.f;
        #pragma unroll
        for (int j = 0; j < 16; ++j) {
            f32x4 v = ((const f32x4*)src)[j];
            s  += v.x + v.y + v.z + v.w;
            s2 += v.x * v.x + v.y * v.y + v.z * v.z + v.w * v.w;
        }
        s  += __shfl_xor(s, 1, 64);  s  += __shfl_xor(s, 2, 64);
        s2 += __shfl_xor(s2, 1, 64); s2 += __shfl_xor(s2, 2, 64);
        float mean = s * (1.0f / 256.0f);
        float var  = s2 * (1.0f / 256.0f) - mean * mean;
        float inv  = rsqrtf(var + LN_EPS);
        const float* gp = g + (l & 3) * 64;
        const float* bp = b + (l & 3) * 64;
        char* arow = As + lr * 512;
        #pragma unroll
        for (int j = 0; j < 8; ++j) {
            f32x4 v0 = ((const f32x4*)src)[2 * j];
            f32x4 v1 = ((const f32x4*)src)[2 * j + 1];
            f32x4 g0 = ((const f32x4*)gp)[2 * j];
            f32x4 g1 = ((const f32x4*)gp)[2 * j + 1];
            f32x4 b0 = ((const f32x4*)bp)[2 * j];
            f32x4 b1 = ((const f32x4*)bp)[2 * j + 1];
            bf16x8 pack;
            pack[0] = f2bf(fmaxf((v0.x - mean) * inv * g0.x + b0.x, 0.f));
            pack[1] = f2bf(fmaxf((v0.y - mean) * inv * g0.y + b0.y, 0.f));
            pack[2] = f2bf(fmaxf((v0.z - mean) * inv * g0.z + b0.z, 0.f));
            pack[3] = f2bf(fmaxf((v0.w - mean) * inv * g0.w + b0.w, 0.f));
            pack[4] = f2bf(fmaxf((v1.x - mean) * inv * g1.x + b1.x, 0.f));
            pack[5] = f2bf(fmaxf((v1.y - mean) * inv * g1.y + b1.y, 0.f));
            pack[6] = f2bf(fmaxf((v1.z - mean) * inv * g1.z + b1.z, 0.f));
            pack[7] = f2bf(fmaxf((v1.w - mean) * inv * g1.w + b1.w, 0.f));
            int boff = (l & 3) * 128 + j * 16;
            *(bf16x8*)(arow + SWZ(lr, boff)) = pack;
        }
    }
    __syncthreads();

    f32x4 acc[8];
    #pragma unroll
    for (int i = 0; i < 8; ++i) acc[i] = (f32x4){0.f, 0.f, 0.f, 0.f};

    const int arow_l = w * 16 + (l & 15);
    const char* abase = As + arow_l * 512;

    for (int h = 0; h < 2; ++h) {
        // stage 64 W rows (32KB) swizzled
        const char* wsrc = (const char*)(Wb + h * 64 * 256);
        #pragma unroll
        for (int i = 0; i < 8; ++i) {
            int c = t + i * 256;               // 0..2047 16B-chunks
            int lrow = c >> 5;
            int boff = (c & 31) * 16;
            bf16x8 val = *(const bf16x8*)(wsrc + lrow * 512 + boff);
            *(bf16x8*)(Wc + lrow * 512 + SWZ(lrow, boff)) = val;
        }
        __syncthreads();

        #pragma unroll
        for (int kc = 0; kc < 8; ++kc) {
            int kb = kc * 64 + (l >> 4) * 16;  // byte offset of 8 bf16 in 512B row
            bf16x8 af = *(const bf16x8*)(abase + SWZ(arow_l, kb));
            #pragma unroll
            for (int nt = 0; nt < 4; ++nt) {
                int lrow = nt * 16 + (l & 15);
                bf16x8 wf = *(const bf16x8*)(Wc + lrow * 512 + SWZ(lrow, kb));
                // D = W x A  -> lane holds out[row=(l&15)][4 consecutive cols]
                acc[h * 4 + nt] = __builtin_amdgcn_mfma_f32_16x16x32_bf16(wf, af, acc[h * 4 + nt], 0, 0, 0);
            }
        }
        __syncthreads();
    }

    // vectorized store: one row per lane (l&15), 4 consecutive cols per acc reg
    const int orow = rb + w * 16 + (l & 15);
    if (orow < M) {
        float* orp = out + (size_t)orow * 128;
        #pragma unroll
        for (int h = 0; h < 2; ++h)
            #pragma unroll
            for (int nt = 0; nt < 4; ++nt) {
                int c0 = h * 64 + nt * 16 + (l >> 4) * 4;
                *(f32x4*)(orp + c0) = acc[h * 4 + nt];
            }
    }
}

// ---------------- main fused: proj GEMM + gather-combine ----------------
// Structure frozen from R9 (linear block->rows, W+bias in LDS once, monolithic step
// body, tight epilogue; FETCH/WRITE measured ideal). R10 change: wave = 16 rows x
// 64 COLS (col-half split) -> acc[4] not acc[8], halving per-lane live VGPR so
// 4 blocks x 8 waves can be resident (R9: VGPR=100 -> only 2 blocks, occ 22%).
// 8 waves = 4 row-groups x 2 col-halves; 4 steps x 64 rows = 256 rows/block.
// pv/idx loads duplicated by the col-half partner wave: same lines, L1/L2 absorbs.
__global__ __launch_bounds__(512) void k_main(
    const float* __restrict__ pv, const int* __restrict__ vidx, const int* __restrict__ pidx,
    const short* __restrict__ Wp, const float* __restrict__ bias,
    const float* __restrict__ spp, const float* __restrict__ vwp,
    float* __restrict__ out, int M)
{
    __shared__ char Wc[32768];             // W_proj bf16 [128][128] swizzled
    __shared__ float bias_s[128];
    const int t  = threadIdx.x;
    const int l  = t & 63;
    const int w  = t >> 6;                 // 0..7
    const int rb = blockIdx.x * 256;       // 256 rows per block

    #pragma unroll
    for (int i = 0; i < 4; ++i) {
        int c = t + i * 512;               // 0..2047 16B-chunks
        int row = c >> 4;
        int boff = (c & 15) * 16;
        bf16x8 val = *(const bf16x8*)((const char*)Wp + row * 256 + boff);
        *(bf16x8*)(Wc + row * 256 + SWZ(row, boff)) = val;
    }
    if (t < 128) bias_s[t] = bias[t];
    __syncthreads();

    const int half   = w & 1;               // output col half (0: cols 0-63, 1: 64-127)
    const int rg     = w >> 1;              // row group 0..3
    const int lane_r = rg * 16 + (l & 15);  // 0..63: row within step
    const int q      = l >> 4;              // col-quad / k-slice selector

    #pragma unroll 1
    for (int s = 0; s < 4; ++s) {
        const int row_l = rb + s * 64 + lane_r;
        const int orow  = min(row_l, M - 1);
        const int pt = pidx[orow];
        const int vw = vidx[orow];

        f32x4 acc[4];
        #pragma unroll
        for (int i = 0; i < 4; ++i) acc[i] = (f32x4){0.f, 0.f, 0.f, 0.f};

        const float* arow_g = pv + (size_t)orow * 128;

        // monolithic MFMA loop: one af fragment live at a time
        #pragma unroll
        for (int kc = 0; kc < 4; ++kc) {
            int k0 = kc * 32 + q * 8;
            f32x4 a0 = *(const f32x4*)(arow_g + k0);
            f32x4 a1 = *(const f32x4*)(arow_g + k0 + 4);
            bf16x8 af;
            af[0] = f2bf(a0.x); af[1] = f2bf(a0.y); af[2] = f2bf(a0.z); af[3] = f2bf(a0.w);
            af[4] = f2bf(a1.x); af[5] = f2bf(a1.y); af[6] = f2bf(a1.z); af[7] = f2bf(a1.w);
            #pragma unroll
            for (int nt = 0; nt < 4; ++nt) {
                int lrow = half * 64 + nt * 16 + (l & 15);   // W row = output col block
                bf16x8 wf = *(const bf16x8*)(Wc + lrow * 256 + SWZ(lrow, k0 * 2));
                acc[nt] = __builtin_amdgcn_mfma_f32_16x16x32_bf16(wf, af, acc[nt], 0, 0, 0);
            }
        }

        // tight epilogue: gathers + combine + stores back-to-back (64 cols per wave)
        if (row_l < M) {
            const float* spr = spp + (size_t)pt * 128;
            const float* vwr = vwp + (size_t)vw * 128;
            float* orp = out + (size_t)orow * 128;
            #pragma unroll
            for (int nt = 0; nt < 4; ++nt) {
                int c0 = half * 64 + nt * 16 + q * 4;
                f32x4 sp4 = *(const f32x4*)(spr + c0);
                f32x4 vw4 = *(const f32x4*)(vwr + c0);
                f32x4 b4  = *(const f32x4*)(bias_s + c0);
                f32x4 r   = (acc[nt] + sp4 + vw4 + b4) * 0.25f;
                *(f32x4*)(orp + c0) = r;
            }
        }
    }
}

extern "C" void kernel_launch(void* const* d_in, const int* in_sizes, int n_in,
                              void* d_out, int out_size, void* d_ws, size_t ws_size,
                              hipStream_t stream) {
    const float* sp_f    = (const float*)d_in[0];
    const float* vw_f    = (const float*)d_in[1];
    const float* gl_f    = (const float*)d_in[2];
    const float* pv      = (const float*)d_in[3];
    const int*   vidx    = (const int*)d_in[4];
    const int*   pidx    = (const int*)d_in[5];
    const float* ln_sp_g = (const float*)d_in[6];
    const float* ln_sp_b = (const float*)d_in[7];
    const float* ln_vw_g = (const float*)d_in[8];
    const float* ln_vw_b = (const float*)d_in[9];
    const float* ln_g_g  = (const float*)d_in[10];
    const float* ln_g_b  = (const float*)d_in[11];
    const float* W_proj  = (const float*)d_in[12];
    const float* b_proj  = (const float*)d_in[13];
    const float* W_sp    = (const float*)d_in[14];
    const float* W_view  = (const float*)d_in[15];
    const float* W_g     = (const float*)d_in[16];

    const int n_pts   = in_sizes[0] / 256;
    const int n_views = in_sizes[1] / 256;
    const int nnz     = in_sizes[3] / 128;

    // ws layout (bytes): [0,163840) W bf16 x3 | [163840,164352) bias | sp_p | vw_p
    short* wbuf = (short*)d_ws;
    float* bias = (float*)((char*)d_ws + 163840);
    float* spp  = (float*)((char*)d_ws + 164352);
    float* vwp  = (float*)((char*)d_ws + 164352 + (size_t)n_pts * 128 * 4);

    k_prep<<<320, 256, 0, stream>>>(W_proj, W_sp, W_view, wbuf);
    k_bias<<<1, 256, 0, stream>>>(gl_f, ln_g_g, ln_g_b, W_g, b_proj, bias);
    k_ln_gemm<<<(n_pts + 63) / 64, 256, 0, stream>>>(sp_f, ln_sp_g, ln_sp_b, wbuf + 16384, spp, n_pts);
    k_ln_gemm<<<(n_views + 63) / 64, 256, 0, stream>>>(vw_f, ln_vw_g, ln_vw_b, wbuf + 49152, vwp, n_views);

    k_main<<<(nnz + 255) / 256, 512, 0, stream>>>(pv, vidx, pidx, wbuf, bias, spp, vwp, (float*)d_out, nnz);
}

// Round 11
// 421.718 us; speedup vs baseline: 1.1998x; 1.1998x over previous
//
#include <hip/hip_runtime.h>
#include <hip/hip_bf16.h>

#define LN_EPS 1e-5f

typedef float  f32x4  __attribute__((ext_vector_type(4)));
typedef short  bf16x8 __attribute__((ext_vector_type(8)));

// RNE float->bf16 (finite inputs)
static __device__ __forceinline__ short f2bf(float x) {
    unsigned u = __float_as_uint(x);
    unsigned r = (u + 0x7fffu + ((u >> 16) & 1u)) >> 16;
    return (short)r;
}

// XOR swizzle: spread 16B chunks of row-major LDS rows across banks
#define SWZ(r, b) ((b) ^ (((r) & 7) << 4))

// ---------------- prep: convert W_proj/W_sp/W_view to bf16 in ws ----------------
__global__ void k_prep(const float* __restrict__ Wp, const float* __restrict__ Ws,
                       const float* __restrict__ Wv, short* __restrict__ wbuf) {
    int i = blockIdx.x * 256 + threadIdx.x;
    if (i < 16384)      wbuf[i] = f2bf(Wp[i]);
    else if (i < 49152) wbuf[i] = f2bf(Ws[i - 16384]);
    else if (i < 81920) wbuf[i] = f2bf(Wv[i - 49152]);
}

// ---------------- bias: LN+ReLU(global row) @ W_g.T + b_proj -> bias[128] ----------------
__global__ void k_bias(const float* __restrict__ gf, const float* __restrict__ gg,
                       const float* __restrict__ gb, const float* __restrict__ Wg,
                       const float* __restrict__ bp, float* __restrict__ bias) {
    __shared__ float sm[256];
    __shared__ float red[8];
    int t = threadIdx.x;
    float x = gf[t];
    float s = x;
    #pragma unroll
    for (int o = 32; o > 0; o >>= 1) s += __shfl_xor(s, o, 64);
    if ((t & 63) == 0) red[t >> 6] = s;
    __syncthreads();
    float m = (red[0] + red[1] + red[2] + red[3]) * (1.0f / 256.0f);
    float d = x - m;
    float q = d * d;
    #pragma unroll
    for (int o = 32; o > 0; o >>= 1) q += __shfl_xor(q, o, 64);
    if ((t & 63) == 0) red[4 + (t >> 6)] = q;
    __syncthreads();
    float v = (red[4] + red[5] + red[6] + red[7]) * (1.0f / 256.0f);
    float n = fmaxf(d * rsqrtf(v + LN_EPS) * gg[t] + gb[t], 0.0f);
    sm[t] = n;
    __syncthreads();
    if (t < 128) {
        float acc = bp[t];
        const float* wrow = Wg + t * 256;
        #pragma unroll 8
        for (int k = 0; k < 256; ++k) acc = fmaf(sm[k], wrow[k], acc);
        bias[t] = acc;
    }
}

// ---------------- fused LN+ReLU+GEMM: A[M][256] -> out[M][128] ----------------
// block = 256 threads, 64 rows/block; W (bf16 [128][256]) staged in 2 halves of 64 rows.
// MFMA computes D = W_frag x A_frag so each lane holds 4 consecutive out-cols of one row.
__global__ __launch_bounds__(256) void k_ln_gemm(
    const float* __restrict__ A, const float* __restrict__ g, const float* __restrict__ b,
    const short* __restrict__ Wb, float* __restrict__ out, int M)
{
    __shared__ char smem[65536];          // [0,32768): A bf16 [64][256] swizzled; [32768,65536): W half
    char* As = smem;
    char* Wc = smem + 32768;

    const int t  = threadIdx.x;
    const int l  = t & 63;
    const int w  = t >> 6;
    const int rb = blockIdx.x * 64;

    // ---- LN + ReLU -> As (bf16, swizzled). 4 lanes per row, 64 cols each ----
    {
        int lr  = w * 16 + (l >> 2);
        int row = min(rb + lr, M - 1);
        const float* src = A + (size_t)row * 256 + (l & 3) * 64;
        float s = 0.f, s2 = 0.f;
        #pragma unroll
        for (int j = 0; j < 16; ++j) {
            f32x4 v = ((const f32x4*)src)[j];
            s  += v.x + v.y + v.z + v.w;
            s2 += v.x * v.x + v.y * v.y + v.z * v.z + v.w * v.w;
        }
        s  += __shfl_xor(s, 1, 64);  s  += __shfl_xor(s, 2, 64);
        s2 += __shfl_xor(s2, 1, 64); s2 += __shfl_xor(s2, 2, 64);
        float mean = s * (1.0f / 256.0f);
        float var  = s2 * (1.0f / 256.0f) - mean * mean;
        float inv  = rsqrtf(var + LN_EPS);
        const float* gp = g + (l & 3) * 64;
        const float* bp = b + (l & 3) * 64;
        char* arow = As + lr * 512;
        #pragma unroll
        for (int j = 0; j < 8; ++j) {
            f32x4 v0 = ((const f32x4*)src)[2 * j];
            f32x4 v1 = ((const f32x4*)src)[2 * j + 1];
            f32x4 g0 = ((const f32x4*)gp)[2 * j];
            f32x4 g1 = ((const f32x4*)gp)[2 * j + 1];
            f32x4 b0 = ((const f32x4*)bp)[2 * j];
            f32x4 b1 = ((const f32x4*)bp)[2 * j + 1];
            bf16x8 pack;
            pack[0] = f2bf(fmaxf((v0.x - mean) * inv * g0.x + b0.x, 0.f));
            pack[1] = f2bf(fmaxf((v0.y - mean) * inv * g0.y + b0.y, 0.f));
            pack[2] = f2bf(fmaxf((v0.z - mean) * inv * g0.z + b0.z, 0.f));
            pack[3] = f2bf(fmaxf((v0.w - mean) * inv * g0.w + b0.w, 0.f));
            pack[4] = f2bf(fmaxf((v1.x - mean) * inv * g1.x + b1.x, 0.f));
            pack[5] = f2bf(fmaxf((v1.y - mean) * inv * g1.y + b1.y, 0.f));
            pack[6] = f2bf(fmaxf((v1.z - mean) * inv * g1.z + b1.z, 0.f));
            pack[7] = f2bf(fmaxf((v1.w - mean) * inv * g1.w + b1.w, 0.f));
            int boff = (l & 3) * 128 + j * 16;
            *(bf16x8*)(arow + SWZ(lr, boff)) = pack;
        }
    }
    __syncthreads();

    f32x4 acc[8];
    #pragma unroll
    for (int i = 0; i < 8; ++i) acc[i] = (f32x4){0.f, 0.f, 0.f, 0.f};

    const int arow_l = w * 16 + (l & 15);
    const char* abase = As + arow_l * 512;

    for (int h = 0; h < 2; ++h) {
        // stage 64 W rows (32KB) swizzled
        const char* wsrc = (const char*)(Wb + h * 64 * 256);
        #pragma unroll
        for (int i = 0; i < 8; ++i) {
            int c = t + i * 256;               // 0..2047 16B-chunks
            int lrow = c >> 5;
            int boff = (c & 31) * 16;
            bf16x8 val = *(const bf16x8*)(wsrc + lrow * 512 + boff);
            *(bf16x8*)(Wc + lrow * 512 + SWZ(lrow, boff)) = val;
        }
        __syncthreads();

        #pragma unroll
        for (int kc = 0; kc < 8; ++kc) {
            int kb = kc * 64 + (l >> 4) * 16;  // byte offset of 8 bf16 in 512B row
            bf16x8 af = *(const bf16x8*)(abase + SWZ(arow_l, kb));
            #pragma unroll
            for (int nt = 0; nt < 4; ++nt) {
                int lrow = nt * 16 + (l & 15);
                bf16x8 wf = *(const bf16x8*)(Wc + lrow * 512 + SWZ(lrow, kb));
                // D = W x A  -> lane holds out[row=(l&15)][4 consecutive cols]
                acc[h * 4 + nt] = __builtin_amdgcn_mfma_f32_16x16x32_bf16(wf, af, acc[h * 4 + nt], 0, 0, 0);
            }
        }
        __syncthreads();
    }

    // vectorized store: one row per lane (l&15), 4 consecutive cols per acc reg
    const int orow = rb + w * 16 + (l & 15);
    if (orow < M) {
        float* orp = out + (size_t)orow * 128;
        #pragma unroll
        for (int h = 0; h < 2; ++h)
            #pragma unroll
            for (int nt = 0; nt < 4; ++nt) {
                int c0 = h * 64 + nt * 16 + (l >> 4) * 4;
                *(f32x4*)(orp + c0) = acc[h * 4 + nt];
            }
    }
}

// ---------------- main fused: proj GEMM + gather-combine (R3 verbatim — best measured) ----------------
// 512 threads = 8 waves x 16 rows -> 128-row tiles, grid-stride persistent, W staged ONCE.
// Measured (R3 bench): 343 us, FETCH 552 MB, WRITE 590 MB, VGPR 100.
// Evidence log: per-nt epilogue spread (R5) and launch_bounds-forced VGPR (R3=40 spill,
// R6=64) inflate FETCH to 1.0-1.2 GB; col-half split (R10) duplicates loads and loses;
// non-persistent variants (R2/R9) are 40-45 us slower. Occupancy is NOT the limiter
// (R10: 44% occ slower than this kernel's 22%). Keep natural register allocation.
__global__ __launch_bounds__(512) void k_main(
    const float* __restrict__ pv, const int* __restrict__ vidx, const int* __restrict__ pidx,
    const short* __restrict__ Wp, const float* __restrict__ bias,
    const float* __restrict__ spp, const float* __restrict__ vwp,
    float* __restrict__ out, int M, int ntiles)
{
    __shared__ char Wc[32768];             // W_proj bf16 [128][128] swizzled
    __shared__ float bias_s[128];
    const int t  = threadIdx.x;
    const int l  = t & 63;
    const int w  = t >> 6;

    #pragma unroll
    for (int i = 0; i < 4; ++i) {
        int c = t + i * 512;               // 0..2047 16B-chunks
        int row = c >> 4;
        int boff = (c & 15) * 16;
        bf16x8 val = *(const bf16x8*)((const char*)Wp + row * 256 + boff);
        *(bf16x8*)(Wc + row * 256 + SWZ(row, boff)) = val;
    }
    if (t < 128) bias_s[t] = bias[t];
    __syncthreads();

    for (int tile = blockIdx.x; tile < ntiles; tile += gridDim.x) {
        const int rb    = tile * 128;
        const int row_l = rb + w * 16 + (l & 15);
        const int orow  = min(row_l, M - 1);
        const int pt = pidx[orow];
        const int vw = vidx[orow];

        f32x4 acc[8];
        #pragma unroll
        for (int i = 0; i < 8; ++i) acc[i] = (f32x4){0.f, 0.f, 0.f, 0.f};

        const float* arow_g = pv + (size_t)orow * 128;

        #pragma unroll
        for (int kc = 0; kc < 4; ++kc) {
            int k0 = kc * 32 + (l >> 4) * 8;
            f32x4 a0 = __builtin_nontemporal_load((const f32x4*)(arow_g + k0));
            f32x4 a1 = __builtin_nontemporal_load((const f32x4*)(arow_g + k0 + 4));
            bf16x8 af;
            af[0] = f2bf(a0.x); af[1] = f2bf(a0.y); af[2] = f2bf(a0.z); af[3] = f2bf(a0.w);
            af[4] = f2bf(a1.x); af[5] = f2bf(a1.y); af[6] = f2bf(a1.z); af[7] = f2bf(a1.w);
            #pragma unroll
            for (int nt = 0; nt < 8; ++nt) {
                int lrow = nt * 16 + (l & 15);
                bf16x8 wf = *(const bf16x8*)(Wc + lrow * 256 + SWZ(lrow, k0 * 2));
                // D = W x pv -> lane holds out[row=(l&15)][4 consecutive cols]
                acc[nt] = __builtin_amdgcn_mfma_f32_16x16x32_bf16(wf, af, acc[nt], 0, 0, 0);
            }
        }

        // vectorized gather-combine epilogue: all f32x4
        if (row_l < M) {
            const float* spr = spp + (size_t)pt * 128;
            const float* vwr = vwp + (size_t)vw * 128;
            float* orp = out + (size_t)orow * 128;
            #pragma unroll
            for (int nt = 0; nt < 8; ++nt) {
                int c0 = nt * 16 + (l >> 4) * 4;
                f32x4 sp4 = *(const f32x4*)(spr + c0);
                f32x4 vw4 = *(const f32x4*)(vwr + c0);
                f32x4 b4  = *(const f32x4*)(bias_s + c0);
                f32x4 r   = acc[nt];
                r = (r + sp4 + vw4 + b4) * 0.25f;
                __builtin_nontemporal_store(r, (f32x4*)(orp + c0));
            }
        }
    }
}

extern "C" void kernel_launch(void* const* d_in, const int* in_sizes, int n_in,
                              void* d_out, int out_size, void* d_ws, size_t ws_size,
                              hipStream_t stream) {
    const float* sp_f    = (const float*)d_in[0];
    const float* vw_f    = (const float*)d_in[1];
    const float* gl_f    = (const float*)d_in[2];
    const float* pv      = (const float*)d_in[3];
    const int*   vidx    = (const int*)d_in[4];
    const int*   pidx    = (const int*)d_in[5];
    const float* ln_sp_g = (const float*)d_in[6];
    const float* ln_sp_b = (const float*)d_in[7];
    const float* ln_vw_g = (const float*)d_in[8];
    const float* ln_vw_b = (const float*)d_in[9];
    const float* ln_g_g  = (const float*)d_in[10];
    const float* ln_g_b  = (const float*)d_in[11];
    const float* W_proj  = (const float*)d_in[12];
    const float* b_proj  = (const float*)d_in[13];
    const float* W_sp    = (const float*)d_in[14];
    const float* W_view  = (const float*)d_in[15];
    const float* W_g     = (const float*)d_in[16];

    const int n_pts   = in_sizes[0] / 256;
    const int n_views = in_sizes[1] / 256;
    const int nnz     = in_sizes[3] / 128;

    // ws layout (bytes): [0,163840) W bf16 x3 | [163840,164352) bias | sp_p | vw_p
    short* wbuf = (short*)d_ws;
    float* bias = (float*)((char*)d_ws + 163840);
    float* spp  = (float*)((char*)d_ws + 164352);
    float* vwp  = (float*)((char*)d_ws + 164352 + (size_t)n_pts * 128 * 4);

    k_prep<<<320, 256, 0, stream>>>(W_proj, W_sp, W_view, wbuf);
    k_bias<<<1, 256, 0, stream>>>(gl_f, ln_g_g, ln_g_b, W_g, b_proj, bias);
    k_ln_gemm<<<(n_pts + 63) / 64, 256, 0, stream>>>(sp_f, ln_sp_g, ln_sp_b, wbuf + 16384, spp, n_pts);
    k_ln_gemm<<<(n_views + 63) / 64, 256, 0, stream>>>(vw_f, ln_vw_g, ln_vw_b, wbuf + 49152, vwp, n_views);

    const int ntiles = (nnz + 127) / 128;
    int grid = ntiles < 1024 ? ntiles : 1024;
    k_main<<<grid, 512, 0, stream>>>(pv, vidx, pidx, wbuf, bias, spp, vwp, (float*)d_out, nnz, ntiles);
}